// Round 1
// baseline (1861.678 us; speedup 1.0000x reference)
//
#include <hip/hip_runtime.h>
#include <hip/hip_bf16.h>

#define NLAYER 4
#define DDIM 256
#define TSEQ 4096
#define NBATCH 8
#define MROWS (NBATCH * TSEQ)   // 32768

typedef float f32x4 __attribute__((ext_vector_type(4)));
typedef short bf16x8 __attribute__((ext_vector_type(8)));

__device__ __forceinline__ float bf2f(unsigned short u) {
    union { unsigned int i; float f; } v; v.i = ((unsigned int)u) << 16; return v.f;
}
__device__ __forceinline__ unsigned short f2bf(float f) {
    union { float f; unsigned int i; } v; v.f = f;
    unsigned int r = v.i + 0x7fffu + ((v.i >> 16) & 1u);
    return (unsigned short)(r >> 16);
}

// ---------------- prepack: weights -> bf16 (gamma folded into B, -C_im), lambda ----------------
__global__ __launch_bounds__(256) void prepack_kernel(
    const float* __restrict__ nu_log, const float* __restrict__ theta_log,
    const float* __restrict__ gamma_log,
    const float* __restrict__ B_re, const float* __restrict__ B_im,
    const float* __restrict__ C_re, const float* __restrict__ C_im,
    const float* __restrict__ Wg,
    unsigned short* __restrict__ wBre, unsigned short* __restrict__ wBim,
    unsigned short* __restrict__ wWg, unsigned short* __restrict__ wCre,
    unsigned short* __restrict__ wCimn,
    float* __restrict__ lam_re, float* __restrict__ lam_im)
{
    int idx = blockIdx.x * 256 + threadIdx.x;
    const int total = NLAYER * DDIM * DDIM;
    if (idx < total) {
        int l = idx >> 16;          // / (256*256)
        int e = (idx >> 8) & 255;   // row (output channel)
        float gam = expf(gamma_log[l * DDIM + e]);
        wBre[idx]  = f2bf(B_re[idx] * gam);
        wBim[idx]  = f2bf(B_im[idx] * gam);
        wWg[idx]   = f2bf(Wg[idx]);
        wCre[idx]  = f2bf(C_re[idx]);
        wCimn[idx] = f2bf(-C_im[idx]);
    }
    if (idx < NLAYER * DDIM) {
        float mag = expf(-expf(nu_log[idx]));
        float th  = expf(theta_log[idx]);
        lam_re[idx] = mag * cosf(th);
        lam_im[idx] = mag * sinf(th);
    }
}

// ---------------- LayerNorm: one wave per row (D=256), 4 rows/block ----------------
__global__ __launch_bounds__(256) void ln_kernel(
    const float* __restrict__ u, unsigned short* __restrict__ z,
    const float* __restrict__ scale, const float* __restrict__ bias)
{
    int wid = threadIdx.x >> 6;
    int lane = threadIdx.x & 63;
    int row = blockIdx.x * 4 + wid;            // 0..MROWS-1
    const float4 v = *reinterpret_cast<const float4*>(u + (size_t)row * DDIM + lane * 4);
    float s  = v.x + v.y + v.z + v.w;
    float s2 = v.x * v.x + v.y * v.y + v.z * v.z + v.w * v.w;
    #pragma unroll
    for (int off = 32; off > 0; off >>= 1) {
        s  += __shfl_xor(s, off);
        s2 += __shfl_xor(s2, off);
    }
    float mu  = s * (1.0f / DDIM);
    float var = s2 * (1.0f / DDIM) - mu * mu;
    float inv = rsqrtf(var + 1e-5f);
    float zv[4] = { v.x, v.y, v.z, v.w };
    ushort4 o;
    unsigned short* op = (unsigned short*)&o;
    #pragma unroll
    for (int j = 0; j < 4; ++j) {
        int d = lane * 4 + j;
        op[j] = f2bf((zv[j] - mu) * inv * scale[d] + bias[d]);
    }
    *reinterpret_cast<ushort4*>(z + (size_t)row * DDIM + lane * 4) = o;
}

// ---------------- GEMM1: z(M,256) x {Bre,Bim,Wg}^T -> bu_re, bu_im, sigmoid(g) (all bf16) ------
// grid: (12, M/128); nb/4 selects matrix, (nb&3)*64 = n0. Tile 128x64, BK=64, 4 waves (2x2).
__global__ __launch_bounds__(256) void gemm1_kernel(
    const unsigned short* __restrict__ z,
    const unsigned short* __restrict__ wBre, const unsigned short* __restrict__ wBim,
    const unsigned short* __restrict__ wWg,
    unsigned short* __restrict__ bure, unsigned short* __restrict__ buim,
    unsigned short* __restrict__ sg)
{
    const int nb = blockIdx.x;
    const int mb = blockIdx.y;
    const int mat = nb >> 2;
    const int n0 = (nb & 3) * 64;
    const unsigned short* W = (mat == 0) ? wBre : ((mat == 1) ? wBim : wWg);
    unsigned short* out = (mat == 0) ? bure : ((mat == 1) ? buim : sg);
    const int m0 = mb * 128;

    __shared__ unsigned short Al[128 * 72];
    __shared__ unsigned short Wl[64 * 72];

    const int tid = threadIdx.x;
    const int lane = tid & 63;
    const int wid = tid >> 6;
    const int wr = wid >> 1, wc = wid & 1;

    f32x4 acc[4][2] = {};

    for (int ko = 0; ko < 256; ko += 64) {
        #pragma unroll
        for (int it = 0; it < 4; ++it) {            // A tile: 128x64 = 1024 chunks of 8
            int c = tid + it * 256;
            int r = c >> 3, kc = (c & 7) * 8;
            bf16x8 v = *reinterpret_cast<const bf16x8*>(z + (size_t)(m0 + r) * 256 + ko + kc);
            *reinterpret_cast<bf16x8*>(&Al[r * 72 + kc]) = v;
        }
        #pragma unroll
        for (int it = 0; it < 2; ++it) {            // W tile: 64x64 = 512 chunks
            int c = tid + it * 256;
            int r = c >> 3, kc = (c & 7) * 8;
            bf16x8 v = *reinterpret_cast<const bf16x8*>(W + (size_t)(n0 + r) * 256 + ko + kc);
            *reinterpret_cast<bf16x8*>(&Wl[r * 72 + kc]) = v;
        }
        __syncthreads();
        #pragma unroll
        for (int k2 = 0; k2 < 64; k2 += 32) {
            int kf = k2 + (lane >> 4) * 8;
            bf16x8 a[4], b[2];
            #pragma unroll
            for (int mi = 0; mi < 4; ++mi)
                a[mi] = *reinterpret_cast<const bf16x8*>(&Al[(wr * 64 + mi * 16 + (lane & 15)) * 72 + kf]);
            #pragma unroll
            for (int ni = 0; ni < 2; ++ni)
                b[ni] = *reinterpret_cast<const bf16x8*>(&Wl[(wc * 32 + ni * 16 + (lane & 15)) * 72 + kf]);
            #pragma unroll
            for (int mi = 0; mi < 4; ++mi)
                #pragma unroll
                for (int ni = 0; ni < 2; ++ni)
                    acc[mi][ni] = __builtin_amdgcn_mfma_f32_16x16x32_bf16(a[mi], b[ni], acc[mi][ni], 0, 0, 0);
        }
        __syncthreads();
    }

    const bool isg = (mat == 2);
    #pragma unroll
    for (int mi = 0; mi < 4; ++mi) {
        #pragma unroll
        for (int ni = 0; ni < 2; ++ni) {
            int col = n0 + wc * 32 + ni * 16 + (lane & 15);
            int mrow = m0 + wr * 64 + mi * 16 + (lane >> 4) * 4;
            #pragma unroll
            for (int j = 0; j < 4; ++j) {
                float v = acc[mi][ni][j];
                if (isg) v = 1.0f / (1.0f + expf(-v));
                out[(size_t)(mrow + j) * 256 + col] = f2bf(v);
            }
        }
    }
}

// ---------------- scan: h[t] = lam*h[t-1] + bu[t], in-place on bf16 planes ----------------
__global__ __launch_bounds__(256) void scan_kernel(
    unsigned short* __restrict__ re, unsigned short* __restrict__ im,
    const float* __restrict__ lam_re, const float* __restrict__ lam_im)
{
    int d = threadIdx.x;
    int b = blockIdx.x;
    float lre = lam_re[d], lim = lam_im[d];
    float hr = 0.0f, hi = 0.0f;
    size_t base = (size_t)b * TSEQ * DDIM + d;
    #pragma unroll 4
    for (int t = 0; t < TSEQ; ++t) {
        size_t idx = base + (size_t)t * DDIM;
        float br = bf2f(re[idx]);
        float bi = bf2f(im[idx]);
        float nhr = lre * hr - lim * hi + br;
        float nhi = lre * hi + lim * hr + bi;
        hr = nhr; hi = nhi;
        re[idx] = f2bf(hr);
        im[idx] = f2bf(hi);
    }
}

// ---------------- GEMM2: y = h_re*C_re^T + h_im*(-C_im)^T; u' = u + (y + Dv*z)*sg ----------------
// grid: (4, M/128). Tile 128x64, BK=64, two K-passes (re, im).
__global__ __launch_bounds__(256) void gemm2_kernel(
    const unsigned short* __restrict__ hre, const unsigned short* __restrict__ him,
    const unsigned short* __restrict__ wCre, const unsigned short* __restrict__ wCimn,
    const unsigned short* __restrict__ z, const unsigned short* __restrict__ sg,
    const float* __restrict__ Dv, const float* __restrict__ uin, float* __restrict__ uout)
{
    const int nb = blockIdx.x;
    const int mb = blockIdx.y;
    const int n0 = nb * 64;
    const int m0 = mb * 128;

    __shared__ unsigned short Al[128 * 72];
    __shared__ unsigned short Wl[64 * 72];

    const int tid = threadIdx.x;
    const int lane = tid & 63;
    const int wid = tid >> 6;
    const int wr = wid >> 1, wc = wid & 1;

    f32x4 acc[4][2] = {};

    for (int pass = 0; pass < 2; ++pass) {
        const unsigned short* A = pass ? him : hre;
        const unsigned short* W = pass ? wCimn : wCre;
        for (int ko = 0; ko < 256; ko += 64) {
            #pragma unroll
            for (int it = 0; it < 4; ++it) {
                int c = tid + it * 256;
                int r = c >> 3, kc = (c & 7) * 8;
                bf16x8 v = *reinterpret_cast<const bf16x8*>(A + (size_t)(m0 + r) * 256 + ko + kc);
                *reinterpret_cast<bf16x8*>(&Al[r * 72 + kc]) = v;
            }
            #pragma unroll
            for (int it = 0; it < 2; ++it) {
                int c = tid + it * 256;
                int r = c >> 3, kc = (c & 7) * 8;
                bf16x8 v = *reinterpret_cast<const bf16x8*>(W + (size_t)(n0 + r) * 256 + ko + kc);
                *reinterpret_cast<bf16x8*>(&Wl[r * 72 + kc]) = v;
            }
            __syncthreads();
            #pragma unroll
            for (int k2 = 0; k2 < 64; k2 += 32) {
                int kf = k2 + (lane >> 4) * 8;
                bf16x8 a[4], b[2];
                #pragma unroll
                for (int mi = 0; mi < 4; ++mi)
                    a[mi] = *reinterpret_cast<const bf16x8*>(&Al[(wr * 64 + mi * 16 + (lane & 15)) * 72 + kf]);
                #pragma unroll
                for (int ni = 0; ni < 2; ++ni)
                    b[ni] = *reinterpret_cast<const bf16x8*>(&Wl[(wc * 32 + ni * 16 + (lane & 15)) * 72 + kf]);
                #pragma unroll
                for (int mi = 0; mi < 4; ++mi)
                    #pragma unroll
                    for (int ni = 0; ni < 2; ++ni)
                        acc[mi][ni] = __builtin_amdgcn_mfma_f32_16x16x32_bf16(a[mi], b[ni], acc[mi][ni], 0, 0, 0);
            }
            __syncthreads();
        }
    }

    #pragma unroll
    for (int mi = 0; mi < 4; ++mi) {
        #pragma unroll
        for (int ni = 0; ni < 2; ++ni) {
            int col = n0 + wc * 32 + ni * 16 + (lane & 15);
            int mrow = m0 + wr * 64 + mi * 16 + (lane >> 4) * 4;
            float dv = Dv[col];
            #pragma unroll
            for (int j = 0; j < 4; ++j) {
                size_t idx = (size_t)(mrow + j) * 256 + col;
                float y = acc[mi][ni][j];
                float zz = bf2f(z[idx]);
                float s = bf2f(sg[idx]);
                uout[idx] = uin[idx] + (y + dv * zz) * s;
            }
        }
    }
}

extern "C" void kernel_launch(void* const* d_in, const int* in_sizes, int n_in,
                              void* d_out, int out_size, void* d_ws, size_t ws_size,
                              hipStream_t stream) {
    const float* x         = (const float*)d_in[0];
    const float* nu_log    = (const float*)d_in[1];
    const float* theta_log = (const float*)d_in[2];
    const float* gamma_log = (const float*)d_in[3];
    const float* B_re      = (const float*)d_in[4];
    const float* B_im      = (const float*)d_in[5];
    const float* C_re      = (const float*)d_in[6];
    const float* C_im      = (const float*)d_in[7];
    const float* D_vec     = (const float*)d_in[8];
    const float* Wg        = (const float*)d_in[9];
    const float* ln_scale  = (const float*)d_in[10];
    const float* ln_bias   = (const float*)d_in[11];
    float* out = (float*)d_out;

    const size_t MSZ = (size_t)MROWS * DDIM;     // 8,388,608 elements
    const size_t WSZ = (size_t)NLAYER * DDIM * DDIM; // 262,144 elements
    unsigned short* b16 = (unsigned short*)d_ws;
    unsigned short* z     = b16;
    unsigned short* sg    = b16 + MSZ;
    unsigned short* hre   = b16 + 2 * MSZ;
    unsigned short* him   = b16 + 3 * MSZ;
    unsigned short* wBre  = b16 + 4 * MSZ;
    unsigned short* wBim  = wBre + WSZ;
    unsigned short* wWg   = wBim + WSZ;
    unsigned short* wCre  = wWg + WSZ;
    unsigned short* wCimn = wCre + WSZ;
    float* lam_re = (float*)(wCimn + WSZ);
    float* lam_im = lam_re + NLAYER * DDIM;

    prepack_kernel<<<1024, 256, 0, stream>>>(nu_log, theta_log, gamma_log,
                                             B_re, B_im, C_re, C_im, Wg,
                                             wBre, wBim, wWg, wCre, wCimn,
                                             lam_re, lam_im);

    for (int l = 0; l < NLAYER; ++l) {
        const float* uin = (l == 0) ? x : out;
        ln_kernel<<<MROWS / 4, 256, 0, stream>>>(uin, z, ln_scale + l * DDIM, ln_bias + l * DDIM);
        gemm1_kernel<<<dim3(12, MROWS / 128), 256, 0, stream>>>(
            z, wBre + l * DDIM * DDIM, wBim + l * DDIM * DDIM, wWg + l * DDIM * DDIM,
            hre, him, sg);
        scan_kernel<<<NBATCH, 256, 0, stream>>>(hre, him, lam_re + l * DDIM, lam_im + l * DDIM);
        gemm2_kernel<<<dim3(4, MROWS / 128), 256, 0, stream>>>(
            hre, him, wCre + l * DDIM * DDIM, wCimn + l * DDIM * DDIM,
            z, sg, D_vec + l * DDIM, uin, out);
    }
}

// Round 2
// 429.552 us; speedup vs baseline: 4.3340x; 4.3340x over previous
//
#include <hip/hip_runtime.h>
#include <hip/hip_bf16.h>

#define NLAYER 4
#define DDIM 256
#define TSEQ 4096
#define NBATCH 8
#define MROWS (NBATCH * TSEQ)   // 32768
#define CLEN 32                 // chunk length for parallel scan
#define NCHUNK (TSEQ / CLEN)    // 128

typedef float f32x4 __attribute__((ext_vector_type(4)));
typedef short bf16x8 __attribute__((ext_vector_type(8)));

__device__ __forceinline__ float bf2f(unsigned short u) {
    union { unsigned int i; float f; } v; v.i = ((unsigned int)u) << 16; return v.f;
}
__device__ __forceinline__ unsigned short f2bf(float f) {
    union { float f; unsigned int i; } v; v.f = f;
    unsigned int r = v.i + 0x7fffu + ((v.i >> 16) & 1u);
    return (unsigned short)(r >> 16);
}

// ---------------- prepack: weights -> bf16 (gamma folded into B, -C_im), lambda, lambda^CLEN ----
__global__ __launch_bounds__(256) void prepack_kernel(
    const float* __restrict__ nu_log, const float* __restrict__ theta_log,
    const float* __restrict__ gamma_log,
    const float* __restrict__ B_re, const float* __restrict__ B_im,
    const float* __restrict__ C_re, const float* __restrict__ C_im,
    const float* __restrict__ Wg,
    unsigned short* __restrict__ wBre, unsigned short* __restrict__ wBim,
    unsigned short* __restrict__ wWg, unsigned short* __restrict__ wCre,
    unsigned short* __restrict__ wCimn,
    float* __restrict__ lam_re, float* __restrict__ lam_im,
    float* __restrict__ lamC_re, float* __restrict__ lamC_im)
{
    int idx = blockIdx.x * 256 + threadIdx.x;
    const int total = NLAYER * DDIM * DDIM;
    if (idx < total) {
        int l = idx >> 16;          // / (256*256)
        int e = (idx >> 8) & 255;   // row (output channel)
        float gam = expf(gamma_log[l * DDIM + e]);
        wBre[idx]  = f2bf(B_re[idx] * gam);
        wBim[idx]  = f2bf(B_im[idx] * gam);
        wWg[idx]   = f2bf(Wg[idx]);
        wCre[idx]  = f2bf(C_re[idx]);
        wCimn[idx] = f2bf(-C_im[idx]);
    }
    if (idx < NLAYER * DDIM) {
        float mag = expf(-expf(nu_log[idx]));
        float th  = expf(theta_log[idx]);
        float ar = mag * cosf(th);
        float ai = mag * sinf(th);
        lam_re[idx] = ar;
        lam_im[idx] = ai;
        // lambda^32 by 5 complex squarings
        #pragma unroll
        for (int s = 0; s < 5; ++s) {
            float nr = ar * ar - ai * ai;
            float ni = 2.0f * ar * ai;
            ar = nr; ai = ni;
        }
        lamC_re[idx] = ar;
        lamC_im[idx] = ai;
    }
}

// ---------------- LayerNorm: one wave per row (D=256), 4 rows/block ----------------
__global__ __launch_bounds__(256) void ln_kernel(
    const float* __restrict__ u, unsigned short* __restrict__ z,
    const float* __restrict__ scale, const float* __restrict__ bias)
{
    int wid = threadIdx.x >> 6;
    int lane = threadIdx.x & 63;
    int row = blockIdx.x * 4 + wid;            // 0..MROWS-1
    const float4 v = *reinterpret_cast<const float4*>(u + (size_t)row * DDIM + lane * 4);
    float s  = v.x + v.y + v.z + v.w;
    float s2 = v.x * v.x + v.y * v.y + v.z * v.z + v.w * v.w;
    #pragma unroll
    for (int off = 32; off > 0; off >>= 1) {
        s  += __shfl_xor(s, off);
        s2 += __shfl_xor(s2, off);
    }
    float mu  = s * (1.0f / DDIM);
    float var = s2 * (1.0f / DDIM) - mu * mu;
    float inv = rsqrtf(var + 1e-5f);
    float zv[4] = { v.x, v.y, v.z, v.w };
    ushort4 o;
    unsigned short* op = (unsigned short*)&o;
    #pragma unroll
    for (int j = 0; j < 4; ++j) {
        int d = lane * 4 + j;
        op[j] = f2bf((zv[j] - mu) * inv * scale[d] + bias[d]);
    }
    *reinterpret_cast<ushort4*>(z + (size_t)row * DDIM + lane * 4) = o;
}

// ---------------- GEMM1: z(M,256) x {Bre,Bim,Wg}^T -> bu_re, bu_im, sigmoid(g) (all bf16) ------
__global__ __launch_bounds__(256) void gemm1_kernel(
    const unsigned short* __restrict__ z,
    const unsigned short* __restrict__ wBre, const unsigned short* __restrict__ wBim,
    const unsigned short* __restrict__ wWg,
    unsigned short* __restrict__ bure, unsigned short* __restrict__ buim,
    unsigned short* __restrict__ sg)
{
    const int nb = blockIdx.x;
    const int mb = blockIdx.y;
    const int mat = nb >> 2;
    const int n0 = (nb & 3) * 64;
    const unsigned short* W = (mat == 0) ? wBre : ((mat == 1) ? wBim : wWg);
    unsigned short* out = (mat == 0) ? bure : ((mat == 1) ? buim : sg);
    const int m0 = mb * 128;

    __shared__ unsigned short Al[128 * 72];
    __shared__ unsigned short Wl[64 * 72];

    const int tid = threadIdx.x;
    const int lane = tid & 63;
    const int wid = tid >> 6;
    const int wr = wid >> 1, wc = wid & 1;

    f32x4 acc[4][2] = {};

    for (int ko = 0; ko < 256; ko += 64) {
        #pragma unroll
        for (int it = 0; it < 4; ++it) {            // A tile: 128x64 = 1024 chunks of 8
            int c = tid + it * 256;
            int r = c >> 3, kc = (c & 7) * 8;
            bf16x8 v = *reinterpret_cast<const bf16x8*>(z + (size_t)(m0 + r) * 256 + ko + kc);
            *reinterpret_cast<bf16x8*>(&Al[r * 72 + kc]) = v;
        }
        #pragma unroll
        for (int it = 0; it < 2; ++it) {            // W tile: 64x64 = 512 chunks
            int c = tid + it * 256;
            int r = c >> 3, kc = (c & 7) * 8;
            bf16x8 v = *reinterpret_cast<const bf16x8*>(W + (size_t)(n0 + r) * 256 + ko + kc);
            *reinterpret_cast<bf16x8*>(&Wl[r * 72 + kc]) = v;
        }
        __syncthreads();
        #pragma unroll
        for (int k2 = 0; k2 < 64; k2 += 32) {
            int kf = k2 + (lane >> 4) * 8;
            bf16x8 a[4], b[2];
            #pragma unroll
            for (int mi = 0; mi < 4; ++mi)
                a[mi] = *reinterpret_cast<const bf16x8*>(&Al[(wr * 64 + mi * 16 + (lane & 15)) * 72 + kf]);
            #pragma unroll
            for (int ni = 0; ni < 2; ++ni)
                b[ni] = *reinterpret_cast<const bf16x8*>(&Wl[(wc * 32 + ni * 16 + (lane & 15)) * 72 + kf]);
            #pragma unroll
            for (int mi = 0; mi < 4; ++mi)
                #pragma unroll
                for (int ni = 0; ni < 2; ++ni)
                    acc[mi][ni] = __builtin_amdgcn_mfma_f32_16x16x32_bf16(a[mi], b[ni], acc[mi][ni], 0, 0, 0);
        }
        __syncthreads();
    }

    const bool isg = (mat == 2);
    #pragma unroll
    for (int mi = 0; mi < 4; ++mi) {
        #pragma unroll
        for (int ni = 0; ni < 2; ++ni) {
            int col = n0 + wc * 32 + ni * 16 + (lane & 15);
            int mrow = m0 + wr * 64 + mi * 16 + (lane >> 4) * 4;
            #pragma unroll
            for (int j = 0; j < 4; ++j) {
                float v = acc[mi][ni][j];
                if (isg) v = 1.0f / (1.0f + expf(-v));
                out[(size_t)(mrow + j) * 256 + col] = f2bf(v);
            }
        }
    }
}

// ---------------- scan phase A: per-chunk local scan (zero init), write chunk finals (f32) -----
__global__ __launch_bounds__(256) void scan_finals_kernel(
    const unsigned short* __restrict__ re, const unsigned short* __restrict__ im,
    float* __restrict__ fin_re, float* __restrict__ fin_im,
    const float* __restrict__ lam_re, const float* __restrict__ lam_im)
{
    const int d = threadIdx.x;
    const int c = blockIdx.x & (NCHUNK - 1);
    const int b = blockIdx.x >> 7;            // NCHUNK = 128
    const float lre = lam_re[d], lim = lam_im[d];
    size_t base = ((size_t)b * TSEQ + (size_t)c * CLEN) * DDIM + d;
    float hr = 0.0f, hi = 0.0f;
    #pragma unroll 8
    for (int k = 0; k < CLEN; ++k) {
        size_t idx = base + (size_t)k * DDIM;
        float br = bf2f(re[idx]);
        float bi = bf2f(im[idx]);
        float nr = fmaf(lre, hr, fmaf(-lim, hi, br));
        float ni = fmaf(lre, hi, fmaf(lim, hr, bi));
        hr = nr; hi = ni;
    }
    fin_re[(size_t)blockIdx.x * DDIM + d] = hr;
    fin_im[(size_t)blockIdx.x * DDIM + d] = hi;
}

// ---------------- scan phase B: exclusive prefix across chunks per (b,d) ----------------
__global__ __launch_bounds__(256) void scan_prefix_kernel(
    const float* __restrict__ fin_re, const float* __restrict__ fin_im,
    float* __restrict__ pre_re, float* __restrict__ pre_im,
    const float* __restrict__ lamC_re, const float* __restrict__ lamC_im)
{
    const int d = threadIdx.x;
    const int b = blockIdx.x;
    const float Lre = lamC_re[d], Lim = lamC_im[d];
    float pr = 0.0f, pi = 0.0f;
    #pragma unroll 4
    for (int c = 0; c < NCHUNK; ++c) {
        size_t idx = ((size_t)b * NCHUNK + c) * DDIM + d;
        pre_re[idx] = pr;
        pre_im[idx] = pi;
        float fr = fin_re[idx];
        float fi = fin_im[idx];
        float nr = fmaf(Lre, pr, fmaf(-Lim, pi, fr));
        float ni = fmaf(Lre, pi, fmaf(Lim, pr, fi));
        pr = nr; pi = ni;
    }
}

// ---------------- scan phase C: re-scan each chunk seeded with prefix, store bf16 in place -----
__global__ __launch_bounds__(256) void scan_apply_kernel(
    unsigned short* __restrict__ re, unsigned short* __restrict__ im,
    const float* __restrict__ pre_re, const float* __restrict__ pre_im,
    const float* __restrict__ lam_re, const float* __restrict__ lam_im)
{
    const int d = threadIdx.x;
    const int c = blockIdx.x & (NCHUNK - 1);
    const int b = blockIdx.x >> 7;
    const float lre = lam_re[d], lim = lam_im[d];
    size_t base = ((size_t)b * TSEQ + (size_t)c * CLEN) * DDIM + d;
    float hr = pre_re[(size_t)blockIdx.x * DDIM + d];
    float hi = pre_im[(size_t)blockIdx.x * DDIM + d];
    #pragma unroll 4
    for (int k = 0; k < CLEN; ++k) {
        size_t idx = base + (size_t)k * DDIM;
        float br = bf2f(re[idx]);
        float bi = bf2f(im[idx]);
        float nr = fmaf(lre, hr, fmaf(-lim, hi, br));
        float ni = fmaf(lre, hi, fmaf(lim, hr, bi));
        hr = nr; hi = ni;
        re[idx] = f2bf(hr);
        im[idx] = f2bf(hi);
    }
}

// ---------------- GEMM2: y = h_re*C_re^T + h_im*(-C_im)^T; u' = u + (y + Dv*z)*sg ----------------
__global__ __launch_bounds__(256) void gemm2_kernel(
    const unsigned short* __restrict__ hre, const unsigned short* __restrict__ him,
    const unsigned short* __restrict__ wCre, const unsigned short* __restrict__ wCimn,
    const unsigned short* __restrict__ z, const unsigned short* __restrict__ sg,
    const float* __restrict__ Dv, const float* __restrict__ uin, float* __restrict__ uout)
{
    const int nb = blockIdx.x;
    const int mb = blockIdx.y;
    const int n0 = nb * 64;
    const int m0 = mb * 128;

    __shared__ unsigned short Al[128 * 72];
    __shared__ unsigned short Wl[64 * 72];

    const int tid = threadIdx.x;
    const int lane = tid & 63;
    const int wid = tid >> 6;
    const int wr = wid >> 1, wc = wid & 1;

    f32x4 acc[4][2] = {};

    for (int pass = 0; pass < 2; ++pass) {
        const unsigned short* A = pass ? him : hre;
        const unsigned short* W = pass ? wCimn : wCre;
        for (int ko = 0; ko < 256; ko += 64) {
            #pragma unroll
            for (int it = 0; it < 4; ++it) {
                int c = tid + it * 256;
                int r = c >> 3, kc = (c & 7) * 8;
                bf16x8 v = *reinterpret_cast<const bf16x8*>(A + (size_t)(m0 + r) * 256 + ko + kc);
                *reinterpret_cast<bf16x8*>(&Al[r * 72 + kc]) = v;
            }
            #pragma unroll
            for (int it = 0; it < 2; ++it) {
                int c = tid + it * 256;
                int r = c >> 3, kc = (c & 7) * 8;
                bf16x8 v = *reinterpret_cast<const bf16x8*>(W + (size_t)(n0 + r) * 256 + ko + kc);
                *reinterpret_cast<bf16x8*>(&Wl[r * 72 + kc]) = v;
            }
            __syncthreads();
            #pragma unroll
            for (int k2 = 0; k2 < 64; k2 += 32) {
                int kf = k2 + (lane >> 4) * 8;
                bf16x8 a[4], b[2];
                #pragma unroll
                for (int mi = 0; mi < 4; ++mi)
                    a[mi] = *reinterpret_cast<const bf16x8*>(&Al[(wr * 64 + mi * 16 + (lane & 15)) * 72 + kf]);
                #pragma unroll
                for (int ni = 0; ni < 2; ++ni)
                    b[ni] = *reinterpret_cast<const bf16x8*>(&Wl[(wc * 32 + ni * 16 + (lane & 15)) * 72 + kf]);
                #pragma unroll
                for (int mi = 0; mi < 4; ++mi)
                    #pragma unroll
                    for (int ni = 0; ni < 2; ++ni)
                        acc[mi][ni] = __builtin_amdgcn_mfma_f32_16x16x32_bf16(a[mi], b[ni], acc[mi][ni], 0, 0, 0);
            }
            __syncthreads();
        }
    }

    #pragma unroll
    for (int mi = 0; mi < 4; ++mi) {
        #pragma unroll
        for (int ni = 0; ni < 2; ++ni) {
            int col = n0 + wc * 32 + ni * 16 + (lane & 15);
            int mrow = m0 + wr * 64 + mi * 16 + (lane >> 4) * 4;
            float dv = Dv[col];
            #pragma unroll
            for (int j = 0; j < 4; ++j) {
                size_t idx = (size_t)(mrow + j) * 256 + col;
                float y = acc[mi][ni][j];
                float zz = bf2f(z[idx]);
                float s = bf2f(sg[idx]);
                uout[idx] = uin[idx] + (y + dv * zz) * s;
            }
        }
    }
}

extern "C" void kernel_launch(void* const* d_in, const int* in_sizes, int n_in,
                              void* d_out, int out_size, void* d_ws, size_t ws_size,
                              hipStream_t stream) {
    const float* x         = (const float*)d_in[0];
    const float* nu_log    = (const float*)d_in[1];
    const float* theta_log = (const float*)d_in[2];
    const float* gamma_log = (const float*)d_in[3];
    const float* B_re      = (const float*)d_in[4];
    const float* B_im      = (const float*)d_in[5];
    const float* C_re      = (const float*)d_in[6];
    const float* C_im      = (const float*)d_in[7];
    const float* D_vec     = (const float*)d_in[8];
    const float* Wg        = (const float*)d_in[9];
    const float* ln_scale  = (const float*)d_in[10];
    const float* ln_bias   = (const float*)d_in[11];
    float* out = (float*)d_out;

    const size_t MSZ = (size_t)MROWS * DDIM;         // 8,388,608 elements
    const size_t WSZ = (size_t)NLAYER * DDIM * DDIM; // 262,144 elements
    const size_t FSZ = (size_t)NBATCH * NCHUNK * DDIM; // 262,144 elements

    unsigned short* b16 = (unsigned short*)d_ws;
    unsigned short* z     = b16;
    unsigned short* sg    = b16 + MSZ;
    unsigned short* hre   = b16 + 2 * MSZ;
    unsigned short* him   = b16 + 3 * MSZ;
    unsigned short* wBre  = b16 + 4 * MSZ;
    unsigned short* wBim  = wBre + WSZ;
    unsigned short* wWg   = wBim + WSZ;
    unsigned short* wCre  = wWg + WSZ;
    unsigned short* wCimn = wCre + WSZ;
    float* lam_re  = (float*)(wCimn + WSZ);
    float* lam_im  = lam_re + NLAYER * DDIM;
    float* lamC_re = lam_im + NLAYER * DDIM;
    float* lamC_im = lamC_re + NLAYER * DDIM;
    float* fin_re  = lamC_im + NLAYER * DDIM;
    float* fin_im  = fin_re + FSZ;
    float* pre_re  = fin_im + FSZ;
    float* pre_im  = pre_re + FSZ;

    prepack_kernel<<<1024, 256, 0, stream>>>(nu_log, theta_log, gamma_log,
                                             B_re, B_im, C_re, C_im, Wg,
                                             wBre, wBim, wWg, wCre, wCimn,
                                             lam_re, lam_im, lamC_re, lamC_im);

    for (int l = 0; l < NLAYER; ++l) {
        const float* uin = (l == 0) ? x : out;
        const float* lre = lam_re + l * DDIM;
        const float* lim = lam_im + l * DDIM;
        ln_kernel<<<MROWS / 4, 256, 0, stream>>>(uin, z, ln_scale + l * DDIM, ln_bias + l * DDIM);
        gemm1_kernel<<<dim3(12, MROWS / 128), 256, 0, stream>>>(
            z, wBre + l * DDIM * DDIM, wBim + l * DDIM * DDIM, wWg + l * DDIM * DDIM,
            hre, him, sg);
        scan_finals_kernel<<<NBATCH * NCHUNK, 256, 0, stream>>>(hre, him, fin_re, fin_im, lre, lim);
        scan_prefix_kernel<<<NBATCH, 256, 0, stream>>>(fin_re, fin_im, pre_re, pre_im,
                                                       lamC_re + l * DDIM, lamC_im + l * DDIM);
        scan_apply_kernel<<<NBATCH * NCHUNK, 256, 0, stream>>>(hre, him, pre_re, pre_im, lre, lim);
        gemm2_kernel<<<dim3(4, MROWS / 128), 256, 0, stream>>>(
            hre, him, wCre + l * DDIM * DDIM, wCimn + l * DDIM * DDIM,
            z, sg, D_vec + l * DDIM, uin, out);
    }
}